// Round 5
// baseline (369.685 us; speedup 1.0000x reference)
//
#include <hip/hip_runtime.h>
#include <math.h>

#define BATCH 8
#define CH 512
#define LEN 2048
#define NG 32
#define CPG 16

typedef unsigned short u16;
typedef __bf16 bf16x8 __attribute__((ext_vector_type(8)));
typedef float f32x16 __attribute__((ext_vector_type(16)));

__device__ __forceinline__ u16 f2bf(float f) {
    union { float f; unsigned u; } c; c.f = f;
    unsigned r = c.u + 0x7fffu + ((c.u >> 16) & 1u);   // RNE
    return (u16)(r >> 16);
}
__device__ __forceinline__ float bf2f(u16 h) {
    union { unsigned u; float f; } c; c.u = ((unsigned)h) << 16;
    return c.f;
}
__device__ __forceinline__ void gload16(const u16* g, u16* l) {
    __builtin_amdgcn_global_load_lds(
        (const __attribute__((address_space(1))) unsigned int*)g,
        (__attribute__((address_space(3))) unsigned int*)l, 16, 0, 0);
}

// ---------------------------------------------------------------------------
__global__ __launch_bounds__(256) void zerof4(float4* __restrict__ p) {
    p[blockIdx.x * 256 + threadIdx.x] = make_float4(0.f, 0.f, 0.f, 0.f);
}

// ---------------------------------------------------------------------------
__global__ __launch_bounds__(256) void wconv4(const float* __restrict__ w0, const float* __restrict__ w1,
                                              const float* __restrict__ w2, const float* __restrict__ w3,
                                              u16* __restrict__ o0, u16* __restrict__ o1,
                                              u16* __restrict__ o2, u16* __restrict__ o3) {
    const float* s; u16* d;
    switch (blockIdx.y) {
        case 0: s = w0; d = o0; break;
        case 1: s = w1; d = o1; break;
        case 2: s = w2; d = o2; break;
        default: s = w3; d = o3; break;
    }
    const int i = blockIdx.x * 256 + threadIdx.x;
    float4 f = ((const float4*)s)[i];
    ushort4 o = make_ushort4(f2bf(f.x), f2bf(f.y), f2bf(f.z), f2bf(f.w));
    ((ushort4*)d)[i] = o;
}

// ---------------------------------------------------------------------------
__global__ __launch_bounds__(256) void gn_stats(const float* __restrict__ x,
                                                const float* __restrict__ gw,
                                                const float* __restrict__ gb,
                                                float* __restrict__ gnA,
                                                float* __restrict__ gnB) {
    const int b = blockIdx.x >> 5, g = blockIdx.x & 31;
    const float4* xp = (const float4*)(x + ((size_t)b * CH + (size_t)g * CPG) * LEN);
    float s = 0.f, s2 = 0.f;
    for (int i = threadIdx.x; i < (CPG * LEN) / 4; i += 256) {
        float4 v = xp[i];
        s += v.x + v.y + v.z + v.w;
        s2 = fmaf(v.x, v.x, fmaf(v.y, v.y, fmaf(v.z, v.z, fmaf(v.w, v.w, s2))));
    }
    #pragma unroll
    for (int off = 32; off > 0; off >>= 1) {
        s  += __shfl_down(s, off, 64);
        s2 += __shfl_down(s2, off, 64);
    }
    __shared__ float sm[2][4];
    const int lane = threadIdx.x & 63, wv = threadIdx.x >> 6;
    if (lane == 0) { sm[0][wv] = s; sm[1][wv] = s2; }
    __syncthreads();
    if (threadIdx.x < CPG) {
        const float S  = sm[0][0] + sm[0][1] + sm[0][2] + sm[0][3];
        const float S2 = sm[1][0] + sm[1][1] + sm[1][2] + sm[1][3];
        const float mean = S * (1.f / (CPG * LEN));
        const float var  = S2 * (1.f / (CPG * LEN)) - mean * mean;
        const float rstd = rsqrtf(var + 1e-6f);
        const int c = g * CPG + threadIdx.x;
        const float sc = rstd * gw[c];
        gnA[b * CH + c] = sc;
        gnB[b * CH + c] = gb[c] - mean * sc;
    }
}

// ---------------------------------------------------------------------------
__global__ __launch_bounds__(256) void gn_apply_t(const float* __restrict__ x,
                                                  const float* __restrict__ gnA,
                                                  const float* __restrict__ gnB,
                                                  u16* __restrict__ Ht) {
    __shared__ float tile[64][65];
    const int b = blockIdx.z, c0 = blockIdx.y * 64, l0 = blockIdx.x * 64;
    const int t = threadIdx.x, tl = t & 63, tr = t >> 6;
    #pragma unroll 4
    for (int i = 0; i < 16; ++i) {
        const int c = tr + i * 4;
        const float a = gnA[b * CH + c0 + c];
        const float sh = gnB[b * CH + c0 + c];
        tile[c][tl] = x[((size_t)b * CH + c0 + c) * LEN + l0 + tl] * a + sh;
    }
    __syncthreads();
    #pragma unroll 4
    for (int i = 0; i < 16; ++i) {
        const int l = tr + i * 4;
        Ht[((size_t)b * LEN + l0 + l) * CH + c0 + tl] = f2bf(tile[tl][l]);
    }
}

// ---------------------------------------------------------------------------
// MFMA GEMM (B^T form), 128x128 tile, BK=64, mfma_f32_32x32x16_bf16.
// C[m][n] = sum_k A[m][k]*B[n][k]; output O[n*ldo + m], 4 consecutive m
// packed per store (C/D reg-quads are 4 m-rows).
// ---------------------------------------------------------------------------
#define EPI_QK   0   // bf16; (Out,bias)/(Out2,bias2) by m half; +bias[m]
#define EPI_TBN  1   // bf16; +bias[n]
#define EPI_EXP  2   // bf16; exp(acc*alpha), accumulate rowsum[n]
#define EPI_TNRM 3   // bf16; * (1/rowsum[n])
#define EPI_FIN  4   // f32;  +bias[n] + res

template <int MODE>
__global__ __launch_bounds__(256) void gemm_bt(
    const u16* __restrict__ A, int lda, long long sA,
    const u16* __restrict__ B, int ldb, long long sB,
    void* __restrict__ Out, void* __restrict__ Out2,
    int ldo, long long sO,
    const float* __restrict__ bias, const float* __restrict__ bias2,
    const float* __restrict__ res, long long sR,
    float* __restrict__ rsum, long long sRS,
    int K, float alpha) {
    __shared__ u16 As[128 * 64];   // 16 KB
    __shared__ u16 Bs[128 * 64];   // 16 KB
    const int b = blockIdx.z;
    const int n0 = blockIdx.x * 128, m0 = blockIdx.y * 128;
    A += (size_t)b * sA;
    B += (size_t)b * sB;
    const int t = threadIdx.x;
    const int lane = t & 63, wid = t >> 6;

    // staging: 128 rows x 64 k x 2B = 16KB/tile = 1024 x16B; 4 chunks/thread
    const int rowL = t >> 3, kq = t & 7;        // rows 0..31, k-chunk 0..7
    const u16* gA[4];
    const u16* gB[4];
    u16* lA[4];
    u16* lB[4];
    #pragma unroll
    for (int g = 0; g < 4; ++g) {
        gA[g] = A + (size_t)(m0 + rowL + g * 32) * lda + kq * 8;
        gB[g] = B + (size_t)(n0 + rowL + g * 32) * ldb + kq * 8;
        lA[g] = As + t * 8 + g * 2048;
        lB[g] = Bs + t * 8 + g * 2048;
    }

    f32x16 acc[2][2];
    #pragma unroll
    for (int i = 0; i < 2; ++i)
        #pragma unroll
        for (int j = 0; j < 2; ++j)
            acc[i][j] = (f32x16)(0.f);

    const int col = lane & 31, half = lane >> 5;
    const int wm = (wid & 1) * 64, wn = (wid >> 1) * 64;
    const int mf = wm + col, nf = wn + col;
    const int kb = half * 8;

    for (int k0 = 0; k0 < K; k0 += 64) {
        #pragma unroll
        for (int g = 0; g < 4; ++g) {
            gload16(gA[g], lA[g]);
            gload16(gB[g], lB[g]);
            gA[g] += 64; gB[g] += 64;
        }
        __syncthreads();
        #pragma unroll
        for (int ks = 0; ks < 4; ++ks) {
            bf16x8 a0 = *(const bf16x8*)(As + (mf)      * 64 + ks * 16 + kb);
            bf16x8 a1 = *(const bf16x8*)(As + (mf + 32) * 64 + ks * 16 + kb);
            bf16x8 b0 = *(const bf16x8*)(Bs + (nf)      * 64 + ks * 16 + kb);
            bf16x8 b1 = *(const bf16x8*)(Bs + (nf + 32) * 64 + ks * 16 + kb);
            acc[0][0] = __builtin_amdgcn_mfma_f32_32x32x16_bf16(a0, b0, acc[0][0], 0, 0, 0);
            acc[0][1] = __builtin_amdgcn_mfma_f32_32x32x16_bf16(a0, b1, acc[0][1], 0, 0, 0);
            acc[1][0] = __builtin_amdgcn_mfma_f32_32x32x16_bf16(a1, b0, acc[1][0], 0, 0, 0);
            acc[1][1] = __builtin_amdgcn_mfma_f32_32x32x16_bf16(a1, b1, acc[1][1], 0, 0, 0);
        }
        __syncthreads();
    }

    // C/D: col = lane&31 (n), row = (reg&3) + 8*(reg>>2) + 4*half (+ 32*i_m)
    if (MODE == EPI_FIN) {
        float* O = (float*)Out + (size_t)b * sO;
        const float* R = res + (size_t)b * sR;
        #pragma unroll
        for (int im = 0; im < 2; ++im)
            #pragma unroll
            for (int g4 = 0; g4 < 4; ++g4) {
                const int mb = m0 + wm + im * 32 + g4 * 8 + half * 4;
                #pragma unroll
                for (int jn = 0; jn < 2; ++jn) {
                    const int n = n0 + wn + jn * 32 + col;
                    const float bb = bias[n];
                    const size_t base = (size_t)n * ldo + mb;
                    const float4 r4 = *(const float4*)&R[base];
                    float4 o4;
                    o4.x = acc[im][jn][g4 * 4 + 0] + bb + r4.x;
                    o4.y = acc[im][jn][g4 * 4 + 1] + bb + r4.y;
                    o4.z = acc[im][jn][g4 * 4 + 2] + bb + r4.z;
                    o4.w = acc[im][jn][g4 * 4 + 3] + bb + r4.w;
                    *(float4*)&O[base] = o4;
                }
            }
    } else if (MODE == EPI_EXP) {
        u16* O = (u16*)Out + (size_t)b * sO;
        float* RS = rsum + (size_t)b * sRS;
        float psum[2] = {0.f, 0.f};
        #pragma unroll
        for (int im = 0; im < 2; ++im)
            #pragma unroll
            for (int g4 = 0; g4 < 4; ++g4) {
                const int mb = m0 + wm + im * 32 + g4 * 8 + half * 4;
                #pragma unroll
                for (int jn = 0; jn < 2; ++jn) {
                    const int n = n0 + wn + jn * 32 + col;
                    u16 h0 = f2bf(__expf(acc[im][jn][g4 * 4 + 0] * alpha));
                    u16 h1 = f2bf(__expf(acc[im][jn][g4 * 4 + 1] * alpha));
                    u16 h2 = f2bf(__expf(acc[im][jn][g4 * 4 + 2] * alpha));
                    u16 h3 = f2bf(__expf(acc[im][jn][g4 * 4 + 3] * alpha));
                    psum[jn] += bf2f(h0) + bf2f(h1) + bf2f(h2) + bf2f(h3);
                    *(ushort4*)&O[(size_t)n * ldo + mb] = make_ushort4(h0, h1, h2, h3);
                }
            }
        #pragma unroll
        for (int jn = 0; jn < 2; ++jn) psum[jn] += __shfl_xor(psum[jn], 32, 64);
        if (half == 0) {
            #pragma unroll
            for (int jn = 0; jn < 2; ++jn)
                atomicAdd(&RS[n0 + wn + jn * 32 + col], psum[jn]);
        }
    } else {
        u16* O;
        const float* bi = bias;
        const float* RS = (MODE == EPI_TNRM) ? rsum + (size_t)b * sRS : nullptr;
        int mbase = m0 + wm;
        if (MODE == EPI_QK) {
            const bool hi = (m0 & 512) != 0;
            O  = (u16*)(hi ? Out2 : Out) + (size_t)b * sO;
            bi = hi ? bias2 : bias;
            mbase = (m0 & 511) + wm;
        } else {
            O = (u16*)Out + (size_t)b * sO;
        }
        float inv[2];
        if (MODE == EPI_TNRM) {
            inv[0] = 1.f / RS[n0 + wn + col];
            inv[1] = 1.f / RS[n0 + wn + 32 + col];
        }
        #pragma unroll
        for (int im = 0; im < 2; ++im)
            #pragma unroll
            for (int g4 = 0; g4 < 4; ++g4) {
                const int mb = mbase + im * 32 + g4 * 8 + half * 4;
                float4 bm = make_float4(0.f, 0.f, 0.f, 0.f);
                if (MODE == EPI_QK) bm = *(const float4*)&bi[mb];
                #pragma unroll
                for (int jn = 0; jn < 2; ++jn) {
                    const int n = n0 + wn + jn * 32 + col;
                    float v0 = acc[im][jn][g4 * 4 + 0];
                    float v1 = acc[im][jn][g4 * 4 + 1];
                    float v2 = acc[im][jn][g4 * 4 + 2];
                    float v3 = acc[im][jn][g4 * 4 + 3];
                    if (MODE == EPI_QK)  { v0 += bm.x; v1 += bm.y; v2 += bm.z; v3 += bm.w; }
                    if (MODE == EPI_TBN) { const float bb = bi[n]; v0 += bb; v1 += bb; v2 += bb; v3 += bb; }
                    if (MODE == EPI_TNRM) { v0 *= inv[jn]; v1 *= inv[jn]; v2 *= inv[jn]; v3 *= inv[jn]; }
                    ushort4 pk = make_ushort4(f2bf(v0), f2bf(v1), f2bf(v2), f2bf(v3));
                    *(ushort4*)&O[(size_t)n * ldo + mb] = pk;
                }
            }
    }
}

// ---------------------------------------------------------------------------
extern "C" void kernel_launch(void* const* d_in, const int* in_sizes, int n_in,
                              void* d_out, int out_size, void* d_ws, size_t ws_size,
                              hipStream_t stream) {
    const float* x    = (const float*)d_in[0];
    const float* gn_w = (const float*)d_in[1];
    const float* gn_b = (const float*)d_in[2];
    const float* wq   = (const float*)d_in[3];
    const float* bq   = (const float*)d_in[4];
    const float* wk   = (const float*)d_in[5];
    const float* bk   = (const float*)d_in[6];
    const float* wv   = (const float*)d_in[7];
    const float* bv   = (const float*)d_in[8];
    const float* wo   = (const float*)d_in[9];
    const float* bo   = (const float*)d_in[10];
    float* out = (float*)d_out;

    char* p = (char*)d_ws;
    const size_t WSZ = (size_t)CH * CH * 2;
    const size_t HSZ = (size_t)BATCH * CH * LEN * 2;
    u16* Wqk = (u16*)p; p += 2 * WSZ;   // rows 0-511 = Wq, 512-1023 = Wk
    u16* Wvb = (u16*)p; p += WSZ;
    u16* Wob = (u16*)p; p += WSZ;
    u16* Ht  = (u16*)p; p += HSZ;   // GN out [b][l][c]; later PV out [b][i][c]
    u16* Qt  = (u16*)p; p += HSZ;   // [b][l][c]
    u16* Kt  = (u16*)p; p += HSZ;   // [b][l][c]
    u16* Vb  = (u16*)p; p += HSZ;   // [b][c][l]
    u16* Sb  = (u16*)p; p += (size_t)BATCH * LEN * LEN * 2;  // exp(scores)
    float* gnA = (float*)p; p += (size_t)BATCH * CH * 4;
    float* gnB = (float*)p; p += (size_t)BATCH * CH * 4;
    float* rowsum = (float*)p;      // BATCH * LEN fp32

    const long long sH = (long long)LEN * CH;
    const long long sV = (long long)CH * LEN;
    const long long sS = (long long)LEN * LEN;
    const float scale = 0.04419417382415922f;   // 512^-0.5

    wconv4<<<dim3(256, 4), 256, 0, stream>>>(wq, wk, wv, wo,
                                             Wqk, Wqk + (size_t)CH * CH, Wvb, Wob);
    gn_stats<<<BATCH * NG, 256, 0, stream>>>(x, gn_w, gn_b, gnA, gnB);
    gn_apply_t<<<dim3(LEN / 64, CH / 64, BATCH), 256, 0, stream>>>(x, gnA, gnB, Ht);
    zerof4<<<BATCH * LEN / 1024, 256, 0, stream>>>((float4*)rowsum);

    // Q+K fused: A=Wqk (m=o), B=Ht (n=l) -> Qt/Kt[l][o] packed in o
    gemm_bt<EPI_QK><<<dim3(16, 8, 8), 256, 0, stream>>>(
        Wqk, CH, 0, Ht, CH, sH, Qt, Kt, CH, sH, bq, bk, nullptr, 0, nullptr, 0, CH, 0.f);
    // V: A=Ht (m=l), B=Wv (n=c) -> Vb[c][l] packed in l, bias[c]
    gemm_bt<EPI_TBN><<<dim3(4, 16, 8), 256, 0, stream>>>(
        Ht, CH, sH, Wvb, CH, 0, Vb, nullptr, LEN, sV, bv, nullptr, nullptr, 0, nullptr, 0, CH, 0.f);
    // scores: A=Kt (m=j), B=Qt (n=i) -> E[i][j]=exp(scale*S) packed in j, rowsum[i]
    gemm_bt<EPI_EXP><<<dim3(16, 16, 8), 256, 0, stream>>>(
        Kt, CH, sH, Qt, CH, sH, Sb, nullptr, LEN, sS, nullptr, nullptr, nullptr, 0, rowsum, LEN, CH, scale);
    // PV: A=Vb (m=c), B=E (n=i) -> Ht[i][c] packed in c, * 1/rowsum[i]
    gemm_bt<EPI_TNRM><<<dim3(16, 4, 8), 256, 0, stream>>>(
        Vb, LEN, sV, Sb, LEN, sS, Ht, nullptr, CH, sH, nullptr, nullptr, nullptr, 0, rowsum, LEN, LEN, 0.f);
    // final: A=Ht (m=l), B=Wo (n=o) -> out[o][l] f32 + bias[o] + x residual
    gemm_bt<EPI_FIN><<<dim3(4, 16, 8), 256, 0, stream>>>(
        Ht, CH, sH, Wob, CH, 0, out, nullptr, LEN, sV, bo, nullptr, x, sV, nullptr, 0, CH, 0.f);
}

// Round 6
// 301.750 us; speedup vs baseline: 1.2251x; 1.2251x over previous
//
#include <hip/hip_runtime.h>
#include <math.h>

#define BATCH 8
#define CH 512
#define LEN 2048
#define NG 32
#define CPG 16

typedef unsigned short u16;
typedef __bf16 bf16x8 __attribute__((ext_vector_type(8)));
typedef float f32x16 __attribute__((ext_vector_type(16)));

__device__ __forceinline__ u16 f2bf(float f) {
    union { float f; unsigned u; } c; c.f = f;
    unsigned r = c.u + 0x7fffu + ((c.u >> 16) & 1u);   // RNE
    return (u16)(r >> 16);
}
__device__ __forceinline__ float bf2f(u16 h) {
    union { unsigned u; float f; } c; c.u = ((unsigned)h) << 16;
    return c.f;
}
__device__ __forceinline__ void gload16(const u16* g, u16* l) {
    __builtin_amdgcn_global_load_lds(
        (const __attribute__((address_space(1))) unsigned int*)g,
        (__attribute__((address_space(3))) unsigned int*)l, 16, 0, 0);
}

// ---------------------------------------------------------------------------
__global__ __launch_bounds__(256) void zerof4(float4* __restrict__ p) {
    p[blockIdx.x * 256 + threadIdx.x] = make_float4(0.f, 0.f, 0.f, 0.f);
}

// ---------------------------------------------------------------------------
__global__ __launch_bounds__(256) void wconv4(const float* __restrict__ w0, const float* __restrict__ w1,
                                              const float* __restrict__ w2, const float* __restrict__ w3,
                                              u16* __restrict__ o0, u16* __restrict__ o1,
                                              u16* __restrict__ o2, u16* __restrict__ o3) {
    const float* s; u16* d;
    switch (blockIdx.y) {
        case 0: s = w0; d = o0; break;
        case 1: s = w1; d = o1; break;
        case 2: s = w2; d = o2; break;
        default: s = w3; d = o3; break;
    }
    const int i = blockIdx.x * 256 + threadIdx.x;
    float4 f = ((const float4*)s)[i];
    ushort4 o = make_ushort4(f2bf(f.x), f2bf(f.y), f2bf(f.z), f2bf(f.w));
    ((ushort4*)d)[i] = o;
}

// ---------------------------------------------------------------------------
__global__ __launch_bounds__(256) void gn_stats(const float* __restrict__ x,
                                                const float* __restrict__ gw,
                                                const float* __restrict__ gb,
                                                float* __restrict__ gnA,
                                                float* __restrict__ gnB) {
    const int b = blockIdx.x >> 5, g = blockIdx.x & 31;
    const float4* xp = (const float4*)(x + ((size_t)b * CH + (size_t)g * CPG) * LEN);
    float s = 0.f, s2 = 0.f;
    for (int i = threadIdx.x; i < (CPG * LEN) / 4; i += 256) {
        float4 v = xp[i];
        s += v.x + v.y + v.z + v.w;
        s2 = fmaf(v.x, v.x, fmaf(v.y, v.y, fmaf(v.z, v.z, fmaf(v.w, v.w, s2))));
    }
    #pragma unroll
    for (int off = 32; off > 0; off >>= 1) {
        s  += __shfl_down(s, off, 64);
        s2 += __shfl_down(s2, off, 64);
    }
    __shared__ float sm[2][4];
    const int lane = threadIdx.x & 63, wv = threadIdx.x >> 6;
    if (lane == 0) { sm[0][wv] = s; sm[1][wv] = s2; }
    __syncthreads();
    if (threadIdx.x < CPG) {
        const float S  = sm[0][0] + sm[0][1] + sm[0][2] + sm[0][3];
        const float S2 = sm[1][0] + sm[1][1] + sm[1][2] + sm[1][3];
        const float mean = S * (1.f / (CPG * LEN));
        const float var  = S2 * (1.f / (CPG * LEN)) - mean * mean;
        const float rstd = rsqrtf(var + 1e-6f);
        const int c = g * CPG + threadIdx.x;
        const float sc = rstd * gw[c];
        gnA[b * CH + c] = sc;
        gnB[b * CH + c] = gb[c] - mean * sc;
    }
}

// ---------------------------------------------------------------------------
__global__ __launch_bounds__(256) void gn_apply_t(const float* __restrict__ x,
                                                  const float* __restrict__ gnA,
                                                  const float* __restrict__ gnB,
                                                  u16* __restrict__ Ht) {
    __shared__ float tile[64][65];
    const int b = blockIdx.z, c0 = blockIdx.y * 64, l0 = blockIdx.x * 64;
    const int t = threadIdx.x, tl = t & 63, tr = t >> 6;
    #pragma unroll 4
    for (int i = 0; i < 16; ++i) {
        const int c = tr + i * 4;
        const float a = gnA[b * CH + c0 + c];
        const float sh = gnB[b * CH + c0 + c];
        tile[c][tl] = x[((size_t)b * CH + c0 + c) * LEN + l0 + tl] * a + sh;
    }
    __syncthreads();
    #pragma unroll 4
    for (int i = 0; i < 16; ++i) {
        const int l = tr + i * 4;
        Ht[((size_t)b * LEN + l0 + l) * CH + c0 + tl] = f2bf(tile[tl][l]);
    }
}

// ---------------------------------------------------------------------------
// MFMA GEMM (B^T form), 128x128 tile, BK=64, mfma_f32_32x32x16_bf16.
// LDS k-chunks XOR-swizzled by row (chunk stored at c = kc ^ (row&7)) via the
// GLOBAL source address (global_load_lds dest must stay lane-contiguous).
// Spreads ds_read_b128 of a fixed kc across all 32 banks (8 lanes / 4-bank
// group — same density as the round-4 known-good stride).
// ---------------------------------------------------------------------------
#define EPI_QK   0   // bf16; (Out,bias)/(Out2,bias2) by m half; +bias[m]
#define EPI_TBN  1   // bf16; +bias[n]
#define EPI_EXP  2   // bf16; exp(acc*alpha), accumulate rowsum[n]
#define EPI_TNRM 3   // bf16; * (1/rowsum[n])
#define EPI_FIN  4   // f32;  +bias[n] + res

template <int MODE>
__global__ __launch_bounds__(256) void gemm_bt(
    const u16* __restrict__ A, int lda, long long sA,
    const u16* __restrict__ B, int ldb, long long sB,
    void* __restrict__ Out, void* __restrict__ Out2,
    int ldo, long long sO,
    const float* __restrict__ bias, const float* __restrict__ bias2,
    const float* __restrict__ res, long long sR,
    float* __restrict__ rsum, long long sRS,
    int K, float alpha) {
    __shared__ u16 As[128 * 64];   // 16 KB
    __shared__ u16 Bs[128 * 64];   // 16 KB
    const int b = blockIdx.z;
    const int n0 = blockIdx.x * 128, m0 = blockIdx.y * 128;
    A += (size_t)b * sA;
    B += (size_t)b * sB;
    const int t = threadIdx.x;
    const int lane = t & 63, wid = t >> 6;

    // staging: thread t owns LDS slots (row = t>>3 + g*32, chunk = t&7);
    // source chunk is XOR-swizzled: global chunk = (t&7) ^ (row&7)
    const int rowL = t >> 3, kq = (t & 7) ^ (rowL & 7);
    const u16* gA[4];
    const u16* gB[4];
    u16* lA[4];
    u16* lB[4];
    #pragma unroll
    for (int g = 0; g < 4; ++g) {
        gA[g] = A + (size_t)(m0 + rowL + g * 32) * lda + kq * 8;
        gB[g] = B + (size_t)(n0 + rowL + g * 32) * ldb + kq * 8;
        lA[g] = As + t * 8 + g * 2048;
        lB[g] = Bs + t * 8 + g * 2048;
    }

    f32x16 acc[2][2];
    #pragma unroll
    for (int i = 0; i < 2; ++i)
        #pragma unroll
        for (int j = 0; j < 2; ++j)
            acc[i][j] = (f32x16)(0.f);

    const int col = lane & 31, half = lane >> 5;
    const int wm = (wid & 1) * 64, wn = (wid >> 1) * 64;
    const int mf = wm + col, nf = wn + col;
    const int mswz = mf & 7, nswz = nf & 7;   // row-invariant mod 8 for +32 rows

    for (int k0 = 0; k0 < K; k0 += 64) {
        #pragma unroll
        for (int g = 0; g < 4; ++g) {
            gload16(gA[g], lA[g]);
            gload16(gB[g], lB[g]);
            gA[g] += 64; gB[g] += 64;
        }
        __syncthreads();
        #pragma unroll
        for (int ks = 0; ks < 4; ++ks) {
            const int kcA = ((ks * 2 + half) ^ mswz) * 8;
            const int kcB = ((ks * 2 + half) ^ nswz) * 8;
            bf16x8 a0 = *(const bf16x8*)(As + (mf)      * 64 + kcA);
            bf16x8 a1 = *(const bf16x8*)(As + (mf + 32) * 64 + kcA);
            bf16x8 b0 = *(const bf16x8*)(Bs + (nf)      * 64 + kcB);
            bf16x8 b1 = *(const bf16x8*)(Bs + (nf + 32) * 64 + kcB);
            acc[0][0] = __builtin_amdgcn_mfma_f32_32x32x16_bf16(a0, b0, acc[0][0], 0, 0, 0);
            acc[0][1] = __builtin_amdgcn_mfma_f32_32x32x16_bf16(a0, b1, acc[0][1], 0, 0, 0);
            acc[1][0] = __builtin_amdgcn_mfma_f32_32x32x16_bf16(a1, b0, acc[1][0], 0, 0, 0);
            acc[1][1] = __builtin_amdgcn_mfma_f32_32x32x16_bf16(a1, b1, acc[1][1], 0, 0, 0);
        }
        __syncthreads();
    }

    // C/D: col = lane&31 (n), row = (reg&3) + 8*(reg>>2) + 4*half (+ 32*i_m)
    if (MODE == EPI_FIN) {
        float* O = (float*)Out + (size_t)b * sO;
        const float* R = res + (size_t)b * sR;
        #pragma unroll
        for (int im = 0; im < 2; ++im)
            #pragma unroll
            for (int g4 = 0; g4 < 4; ++g4) {
                const int mb = m0 + wm + im * 32 + g4 * 8 + half * 4;
                #pragma unroll
                for (int jn = 0; jn < 2; ++jn) {
                    const int n = n0 + wn + jn * 32 + col;
                    const float bb = bias[n];
                    const size_t base = (size_t)n * ldo + mb;
                    const float4 r4 = *(const float4*)&R[base];
                    float4 o4;
                    o4.x = acc[im][jn][g4 * 4 + 0] + bb + r4.x;
                    o4.y = acc[im][jn][g4 * 4 + 1] + bb + r4.y;
                    o4.z = acc[im][jn][g4 * 4 + 2] + bb + r4.z;
                    o4.w = acc[im][jn][g4 * 4 + 3] + bb + r4.w;
                    *(float4*)&O[base] = o4;
                }
            }
    } else if (MODE == EPI_EXP) {
        u16* O = (u16*)Out + (size_t)b * sO;
        float* RS = rsum + (size_t)b * sRS;
        float psum[2] = {0.f, 0.f};
        #pragma unroll
        for (int im = 0; im < 2; ++im)
            #pragma unroll
            for (int g4 = 0; g4 < 4; ++g4) {
                const int mb = m0 + wm + im * 32 + g4 * 8 + half * 4;
                #pragma unroll
                for (int jn = 0; jn < 2; ++jn) {
                    const int n = n0 + wn + jn * 32 + col;
                    u16 h0 = f2bf(__expf(acc[im][jn][g4 * 4 + 0] * alpha));
                    u16 h1 = f2bf(__expf(acc[im][jn][g4 * 4 + 1] * alpha));
                    u16 h2 = f2bf(__expf(acc[im][jn][g4 * 4 + 2] * alpha));
                    u16 h3 = f2bf(__expf(acc[im][jn][g4 * 4 + 3] * alpha));
                    psum[jn] += bf2f(h0) + bf2f(h1) + bf2f(h2) + bf2f(h3);
                    *(ushort4*)&O[(size_t)n * ldo + mb] = make_ushort4(h0, h1, h2, h3);
                }
            }
        #pragma unroll
        for (int jn = 0; jn < 2; ++jn) psum[jn] += __shfl_xor(psum[jn], 32, 64);
        if (half == 0) {
            #pragma unroll
            for (int jn = 0; jn < 2; ++jn)
                atomicAdd(&RS[n0 + wn + jn * 32 + col], psum[jn]);
        }
    } else {
        u16* O;
        const float* bi = bias;
        const float* RS = (MODE == EPI_TNRM) ? rsum + (size_t)b * sRS : nullptr;
        int mbase = m0 + wm;
        if (MODE == EPI_QK) {
            const bool hi = (m0 & 512) != 0;
            O  = (u16*)(hi ? Out2 : Out) + (size_t)b * sO;
            bi = hi ? bias2 : bias;
            mbase = (m0 & 511) + wm;
        } else {
            O = (u16*)Out + (size_t)b * sO;
        }
        float inv[2];
        if (MODE == EPI_TNRM) {
            inv[0] = 1.f / RS[n0 + wn + col];
            inv[1] = 1.f / RS[n0 + wn + 32 + col];
        }
        #pragma unroll
        for (int im = 0; im < 2; ++im)
            #pragma unroll
            for (int g4 = 0; g4 < 4; ++g4) {
                const int mb = mbase + im * 32 + g4 * 8 + half * 4;
                float4 bm = make_float4(0.f, 0.f, 0.f, 0.f);
                if (MODE == EPI_QK) bm = *(const float4*)&bi[mb];
                #pragma unroll
                for (int jn = 0; jn < 2; ++jn) {
                    const int n = n0 + wn + jn * 32 + col;
                    float v0 = acc[im][jn][g4 * 4 + 0];
                    float v1 = acc[im][jn][g4 * 4 + 1];
                    float v2 = acc[im][jn][g4 * 4 + 2];
                    float v3 = acc[im][jn][g4 * 4 + 3];
                    if (MODE == EPI_QK)  { v0 += bm.x; v1 += bm.y; v2 += bm.z; v3 += bm.w; }
                    if (MODE == EPI_TBN) { const float bb = bi[n]; v0 += bb; v1 += bb; v2 += bb; v3 += bb; }
                    if (MODE == EPI_TNRM) { v0 *= inv[jn]; v1 *= inv[jn]; v2 *= inv[jn]; v3 *= inv[jn]; }
                    ushort4 pk = make_ushort4(f2bf(v0), f2bf(v1), f2bf(v2), f2bf(v3));
                    *(ushort4*)&O[(size_t)n * ldo + mb] = pk;
                }
            }
    }
}

// ---------------------------------------------------------------------------
extern "C" void kernel_launch(void* const* d_in, const int* in_sizes, int n_in,
                              void* d_out, int out_size, void* d_ws, size_t ws_size,
                              hipStream_t stream) {
    const float* x    = (const float*)d_in[0];
    const float* gn_w = (const float*)d_in[1];
    const float* gn_b = (const float*)d_in[2];
    const float* wq   = (const float*)d_in[3];
    const float* bq   = (const float*)d_in[4];
    const float* wk   = (const float*)d_in[5];
    const float* bk   = (const float*)d_in[6];
    const float* wv   = (const float*)d_in[7];
    const float* bv   = (const float*)d_in[8];
    const float* wo   = (const float*)d_in[9];
    const float* bo   = (const float*)d_in[10];
    float* out = (float*)d_out;

    char* p = (char*)d_ws;
    const size_t WSZ = (size_t)CH * CH * 2;
    const size_t HSZ = (size_t)BATCH * CH * LEN * 2;
    u16* Wqk = (u16*)p; p += 2 * WSZ;   // rows 0-511 = Wq, 512-1023 = Wk
    u16* Wvb = (u16*)p; p += WSZ;
    u16* Wob = (u16*)p; p += WSZ;
    u16* Ht  = (u16*)p; p += HSZ;   // GN out [b][l][c]; later PV out [b][i][c]
    u16* Qt  = (u16*)p; p += HSZ;   // [b][l][c]
    u16* Kt  = (u16*)p; p += HSZ;   // [b][l][c]
    u16* Vb  = (u16*)p; p += HSZ;   // [b][c][l]
    u16* Sb  = (u16*)p; p += (size_t)BATCH * LEN * LEN * 2;  // exp(scores)
    float* gnA = (float*)p; p += (size_t)BATCH * CH * 4;
    float* gnB = (float*)p; p += (size_t)BATCH * CH * 4;
    float* rowsum = (float*)p;      // BATCH * LEN fp32

    const long long sH = (long long)LEN * CH;
    const long long sV = (long long)CH * LEN;
    const long long sS = (long long)LEN * LEN;
    const float scale = 0.04419417382415922f;   // 512^-0.5

    wconv4<<<dim3(256, 4), 256, 0, stream>>>(wq, wk, wv, wo,
                                             Wqk, Wqk + (size_t)CH * CH, Wvb, Wob);
    gn_stats<<<BATCH * NG, 256, 0, stream>>>(x, gn_w, gn_b, gnA, gnB);
    gn_apply_t<<<dim3(LEN / 64, CH / 64, BATCH), 256, 0, stream>>>(x, gnA, gnB, Ht);
    zerof4<<<BATCH * LEN / 1024, 256, 0, stream>>>((float4*)rowsum);

    // Q+K fused: A=Wqk (m=o), B=Ht (n=l) -> Qt/Kt[l][o] packed in o
    gemm_bt<EPI_QK><<<dim3(16, 8, 8), 256, 0, stream>>>(
        Wqk, CH, 0, Ht, CH, sH, Qt, Kt, CH, sH, bq, bk, nullptr, 0, nullptr, 0, CH, 0.f);
    // V: A=Ht (m=l), B=Wv (n=c) -> Vb[c][l] packed in l, bias[c]
    gemm_bt<EPI_TBN><<<dim3(4, 16, 8), 256, 0, stream>>>(
        Ht, CH, sH, Wvb, CH, 0, Vb, nullptr, LEN, sV, bv, nullptr, nullptr, 0, nullptr, 0, CH, 0.f);
    // scores: A=Kt (m=j), B=Qt (n=i) -> E[i][j]=exp(scale*S) packed in j, rowsum[i]
    gemm_bt<EPI_EXP><<<dim3(16, 16, 8), 256, 0, stream>>>(
        Kt, CH, sH, Qt, CH, sH, Sb, nullptr, LEN, sS, nullptr, nullptr, nullptr, 0, rowsum, LEN, CH, scale);
    // PV: A=Vb (m=c), B=E (n=i) -> Ht[i][c] packed in c, * 1/rowsum[i]
    gemm_bt<EPI_TNRM><<<dim3(16, 4, 8), 256, 0, stream>>>(
        Vb, LEN, sV, Sb, LEN, sS, Ht, nullptr, CH, sH, nullptr, nullptr, nullptr, 0, rowsum, LEN, LEN, 0.f);
    // final: A=Ht (m=l), B=Wo (n=o) -> out[o][l] f32 + bias[o] + x residual
    gemm_bt<EPI_FIN><<<dim3(4, 16, 8), 256, 0, stream>>>(
        Ht, CH, sH, Wob, CH, 0, out, nullptr, LEN, sV, bo, nullptr, x, sV, nullptr, 0, CH, 0.f);
}